// Round 1
// baseline (26.141 us; speedup 1.0000x reference)
//
#include <hip/hip_runtime.h>

#define BATCHES  256
#define NVIEWS   20
#define CHANNELS 4096
#define KSEL     7
#define NT       1024        // threads/block; CHANNELS/4 == 1024 float4 chunks

__global__ __launch_bounds__(NT) void view_select_kernel(
    const float* __restrict__ F0,     // [B, N, C]
    const float* __restrict__ V0,     // [B, N, 3]
    float* __restrict__ out)          // [B*7*C] ++ [B*7*3]
{
    const int b = blockIdx.x;
    const int t = threadIdx.x;

    __shared__ int counts[NVIEWS];
    __shared__ int sidx[KSEL];

    if (t < NVIEWS) counts[t] = 0;
    __syncthreads();

    // ---- phase 1: per-channel argmax over views + histogram ----
    const float* Fb = F0 + (size_t)b * NVIEWS * CHANNELS;
    const float4* Fb4 = (const float4*)Fb;

    float4 best = Fb4[t];                       // n = 0
    int bi0 = 0, bi1 = 0, bi2 = 0, bi3 = 0;
    #pragma unroll
    for (int n = 1; n < NVIEWS; ++n) {
        float4 v = Fb4[(size_t)n * (CHANNELS/4) + t];
        if (v.x > best.x) { best.x = v.x; bi0 = n; }
        if (v.y > best.y) { best.y = v.y; bi1 = n; }
        if (v.z > best.z) { best.z = v.z; bi2 = n; }
        if (v.w > best.w) { best.w = v.w; bi3 = n; }
    }
    atomicAdd(&counts[bi0], 1);
    atomicAdd(&counts[bi1], 1);
    atomicAdd(&counts[bi2], 1);
    atomicAdd(&counts[bi3], 1);
    __syncthreads();

    // ---- phase 2: view selection (thread 0; 20 bins, trivial) ----
    if (t == 0) {
        int u = 0;
        #pragma unroll
        for (int n = 0; n < NVIEWS; ++n) u += (counts[n] > 0) ? 1 : 0;

        if (u >= KSEL) {
            // top-7 by count, ties -> lower view id (== lax.top_k semantics)
            int c[NVIEWS];
            #pragma unroll
            for (int n = 0; n < NVIEWS; ++n) c[n] = counts[n];
            for (int j = 0; j < KSEL; ++j) {
                int bestn = 0, bestc = c[0];
                for (int n = 1; n < NVIEWS; ++n)
                    if (c[n] > bestc) { bestc = c[n]; bestn = n; }
                sidx[j] = bestn;
                c[bestn] = -1;
            }
        } else {
            // sorted unique ids, left-padded with the smallest
            int uniq[NVIEWS]; int m = 0;
            for (int n = 0; n < NVIEWS; ++n)
                if (counts[n] > 0) uniq[m++] = n;
            for (int j = 0; j < KSEL; ++j) {
                int p = j - (KSEL - u);
                if (p < 0) p = 0;
                sidx[j] = uniq[p];
            }
        }
    }
    __syncthreads();

    // ---- phase 3: gather F rows (L1/L2-resident) + vertices ----
    float4* out4 = (float4*)out;
    const size_t ob = (size_t)b * KSEL * (CHANNELS/4);
    #pragma unroll
    for (int j = 0; j < KSEL; ++j) {
        int iv = sidx[j];
        out4[ob + (size_t)j * (CHANNELS/4) + t] =
            Fb4[(size_t)iv * (CHANNELS/4) + t];
    }

    const size_t F_OUT = (size_t)BATCHES * KSEL * CHANNELS;
    if (t < KSEL * 3) {
        int j = t / 3;           // which selected view
        // t % 3 is the coordinate; layout matches directly
        out[F_OUT + (size_t)b * KSEL * 3 + t] =
            V0[(size_t)b * NVIEWS * 3 + (size_t)sidx[j] * 3 + (t % 3)];
    }
}

extern "C" void kernel_launch(void* const* d_in, const int* in_sizes, int n_in,
                              void* d_out, int out_size, void* d_ws, size_t ws_size,
                              hipStream_t stream) {
    const float* F0 = (const float*)d_in[0];
    const float* V0 = (const float*)d_in[1];
    float* out = (float*)d_out;

    view_select_kernel<<<BATCHES, NT, 0, stream>>>(F0, V0, out);
}